// Round 5
// baseline (547.896 us; speedup 1.0000x reference)
//
#include <hip/hip_runtime.h>
#include <hip/hip_cooperative_groups.h>

namespace cg = cooperative_groups;

// GCN layer on MI355X (gfx950) — ALL tensors fp32.
// x[100000,512], edge_index[2,3200000] i32, W1[512,16], b1[16], W2[16,2], b2[2]
//   -> out[100000,2] fp32.
//
// Folds (epilogue is linear):
//   Wc = W1@W2 [512,2],  b' = b1@W2 + b2
//   t_raw[j] = (x@Wc)[j];  after deg known: t[j] = dinv[j]*t_raw[j]
//   out_i = dinv_i * ( sum_{j->i} t_j + t_i ) + b'
//
// R10: single cooperative mega-kernel (grid.sync between phases).
// Rationale: after R9 (371us) every sub-kernel is under the 120us harness
// poison fills => no rocprof visibility; and ~150-200us of the total is
// unattributable (sum of modeled phase costs ~220us << 371us). Fusing
// eliminates 5 launch gaps and produces ONE >120us dispatch whose counters
// are readable next round. Phase algorithms are R9's (verified): LDS
// write-combined binning, 4-node/wave xw GEMV, LDS-bucket dinv/acc.
//
// Phases (512-vblock decomposition, grid-stride, G = min(512, occ*256)):
//   P0 hist[512][391] over 6250-edge ranges  ∪  Wc/b' fold (block 0)
//   P1 per-bucket column scan (exclusive offsets in place, coltot)
//   P2 bucket base scan (block 0)
//   P3 bin placement (LDS stage 25KB, run-per-16-lane-group copy-out)
//      ∪ t_raw = x@Wc (4 nodes/wave); bin vblocks first per block
//   P4 per-bucket degree -> dinv, scale t2 in place
//   P5 per-bucket LDS accumulate + fused epilogue

constexpr int N_NODES = 100000;
constexpr int N_EDGES = 3200000;
constexpr int IN_CH   = 512;
constexpr int HID     = 16;
constexpr int OUT_CH  = 2;

constexpr int NBUCK  = (N_NODES + 255) / 256;   // 391 buckets x 256 nodes
constexpr int CNT_VB = 512;                     // hist rows / bin vblocks
constexpr int EPB    = N_EDGES / CNT_VB;        // 6250 (exact)
constexpr int XW_VB  = (N_NODES + 63) / 64;     // 1563 (64 nodes/vblock)

typedef __attribute__((ext_vector_type(4))) float floatx4;

// ---- workspace layout (bytes) ----
// 0        hist     int[512][391]  (800768)
// 800768   coltot   int[391]       (pad to 1568)
// 802336   bbase    int[392]
// 803904   Wc       float[1024]
// 807  -   (4096) ends 808000
// 808000   bconst   float[2] (pad 16)
// 808016   dinv     float[N_NODES]   (400000)
// 1208016  t2       float2[N_NODES]  (800000)
// 2008016  binned   int[N_EDGES]     (12.8 MB)  value = (local_tgt<<20)|src

__global__ __launch_bounds__(1024) void k_mega(const int* __restrict__ ei,
                                               const float* __restrict__ x,
                                               const float* __restrict__ W1,
                                               const float* __restrict__ b1,
                                               const float* __restrict__ W2,
                                               const float* __restrict__ b2,
                                               int* __restrict__ hist,
                                               int* __restrict__ coltot,
                                               int* __restrict__ bbase,
                                               float* __restrict__ Wc,
                                               float* __restrict__ bconst,
                                               float* __restrict__ dinv,
                                               float2* __restrict__ t2,
                                               int* __restrict__ binned,
                                               float2* __restrict__ out) {
    __shared__ int smem[8192];                  // 32 KB arena, overlaid per phase
    cg::grid_group grid = cg::this_grid();
    const int tid = threadIdx.x;
    const int G = gridDim.x;
    const int* tgt = ei + N_EDGES;

    // ---------------- P0: histogram + weight fold ----------------
    for (int v = blockIdx.x; v < CNT_VB; v += G) {
        for (int i = tid; i < NBUCK; i += 1024) smem[i] = 0;
        __syncthreads();
        int e0 = v * EPB;
        for (int e = e0 + tid; e < e0 + EPB; e += 1024)
            atomicAdd(&smem[tgt[e] >> 8], 1);
        __syncthreads();
        for (int i = tid; i < NBUCK; i += 1024)
            hist[v * NBUCK + i] = smem[i];
        __syncthreads();                        // smem reused next iter
    }
    if (blockIdx.x == 0) {                      // Wc = W1@W2, b' = b1@W2+b2
        for (int i = tid; i < IN_CH * OUT_CH; i += 1024) {
            int c = i >> 1, o = i & 1;
            float s = 0.f;
#pragma unroll
            for (int h = 0; h < HID; ++h) s += W1[c * HID + h] * W2[h * OUT_CH + o];
            Wc[i] = s;
        }
        if (tid < OUT_CH) {
            float bo = b2[tid];
#pragma unroll
            for (int h = 0; h < HID; ++h) bo += b1[h] * W2[h * OUT_CH + tid];
            bconst[tid] = bo;
        }
    }
    grid.sync();

    // ---------------- P1: per-bucket column scan ----------------
    for (int b = blockIdx.x; b < NBUCK; b += G) {
        int v = 0;
        if (tid < CNT_VB) v = hist[tid * NBUCK + b];
        if (tid < 512) smem[tid] = v;
        __syncthreads();
#pragma unroll
        for (int off = 1; off < 512; off <<= 1) {
            int tv = (tid < 512 && tid >= off) ? smem[tid - off] : 0;
            __syncthreads();
            if (tid < 512) smem[tid] += tv;
            __syncthreads();
        }
        if (tid < CNT_VB) hist[tid * NBUCK + b] = smem[tid] - v;  // exclusive
        if (tid == 511) coltot[b] = smem[511];
        __syncthreads();
    }
    grid.sync();

    // ---------------- P2: bucket base scan (block 0) ----------------
    if (blockIdx.x == 0) {
        int v = 0;
        if (tid < NBUCK) v = coltot[tid];
        if (tid < 512) smem[tid] = v;
        __syncthreads();
#pragma unroll
        for (int off = 1; off < 512; off <<= 1) {
            int tv = (tid < 512 && tid >= off) ? smem[tid - off] : 0;
            __syncthreads();
            if (tid < 512) smem[tid] += tv;
            __syncthreads();
        }
        if (tid < NBUCK) bbase[tid] = smem[tid] - v;
        if (tid == NBUCK - 1) bbase[NBUCK] = smem[tid];  // = N_EDGES
    }
    grid.sync();

    // ---------------- P3: bin placement ∪ x@Wc ----------------
    for (int v = blockIdx.x; v < CNT_VB + XW_VB; v += G) {
        if (v < CNT_VB) {
            // --- binning with LDS write-combining ---
            int* stage = smem;                  // [0,6250)
            int* goff  = smem + 6272;           // [6272,6663)
            int* rlen  = smem + 6720;           // [6720,7111)
            int* lcur  = smem + 7168;           // [7168,7559)
            int* lofs  = smem + 7616;           // [7616,8128)
            for (int b = tid; b < NBUCK; b += 1024) {
                int g  = hist[v * NBUCK + b];
                int nx = (v == CNT_VB - 1) ? coltot[b] : hist[(v + 1) * NBUCK + b];
                goff[b] = g;
                rlen[b] = nx - g;
            }
            __syncthreads();
            if (tid < 512) lofs[tid] = (tid < NBUCK) ? rlen[tid] : 0;
            __syncthreads();
#pragma unroll
            for (int off = 1; off < 512; off <<= 1) {   // inclusive scan
                int tv = (tid < 512 && tid >= off) ? lofs[tid - off] : 0;
                __syncthreads();
                if (tid < 512) lofs[tid] += tv;
                __syncthreads();
            }
            for (int b = tid; b < NBUCK; b += 1024)
                lcur[b] = lofs[b] - rlen[b];            // exclusive LDS offset
            __syncthreads();
            int e0 = v * EPB;
            for (int e = e0 + tid; e < e0 + EPB; e += 1024) {
                int tg = tgt[e];
                int b = tg >> 8;
                int lpos = atomicAdd(&lcur[b], 1);
                stage[lpos] = ((tg & 255) << 20) | ei[e];  // src < 2^20
            }
            __syncthreads();
            int grp = tid >> 4, li = tid & 15;          // 64 groups x 16 lanes
            for (int b = grp; b < NBUCK; b += 64) {     // run-per-group copy-out
                int len = rlen[b];
                int gbase = bbase[b] + goff[b];
                int lbase = lofs[b] - len;
                for (int i = li; i < len; i += 16)
                    binned[gbase + i] = stage[lbase + i];
            }
            __syncthreads();                            // smem reuse safety
        } else {
            // --- xw: t_raw = x@Wc, 4 nodes per wave ---
            int nb = v - CNT_VB;
            int wv = tid >> 6;
            int lane = tid & 63;
            int node = nb * 64 + wv * 4;
            int r0 = min(node,     N_NODES - 1);
            int r1 = min(node + 1, N_NODES - 1);
            int r2 = min(node + 2, N_NODES - 1);
            int r3 = min(node + 3, N_NODES - 1);
            const floatx4* x0 = reinterpret_cast<const floatx4*>(x + (size_t)r0 * IN_CH + lane * 8);
            const floatx4* x1 = reinterpret_cast<const floatx4*>(x + (size_t)r1 * IN_CH + lane * 8);
            const floatx4* x2 = reinterpret_cast<const floatx4*>(x + (size_t)r2 * IN_CH + lane * 8);
            const floatx4* x3 = reinterpret_cast<const floatx4*>(x + (size_t)r3 * IN_CH + lane * 8);
            const floatx4* wr = reinterpret_cast<const floatx4*>(Wc + lane * 16);
            floatx4 a0 = x0[0], a1 = x0[1];
            floatx4 b0 = x1[0], b1v = x1[1];
            floatx4 c0 = x2[0], c1 = x2[1];
            floatx4 d0 = x3[0], d1 = x3[1];
            floatx4 w0 = wr[0], w1 = wr[1], w2 = wr[2], w3 = wr[3];
            float s0x = a0[0]*w0[0] + a0[1]*w0[2] + a0[2]*w1[0] + a0[3]*w1[2]
                      + a1[0]*w2[0] + a1[1]*w2[2] + a1[2]*w3[0] + a1[3]*w3[2];
            float s0y = a0[0]*w0[1] + a0[1]*w0[3] + a0[2]*w1[1] + a0[3]*w1[3]
                      + a1[0]*w2[1] + a1[1]*w2[3] + a1[2]*w3[1] + a1[3]*w3[3];
            float s1x = b0[0]*w0[0] + b0[1]*w0[2] + b0[2]*w1[0] + b0[3]*w1[2]
                      + b1v[0]*w2[0] + b1v[1]*w2[2] + b1v[2]*w3[0] + b1v[3]*w3[2];
            float s1y = b0[0]*w0[1] + b0[1]*w0[3] + b0[2]*w1[1] + b0[3]*w1[3]
                      + b1v[0]*w2[1] + b1v[1]*w2[3] + b1v[2]*w3[1] + b1v[3]*w3[3];
            float s2x = c0[0]*w0[0] + c0[1]*w0[2] + c0[2]*w1[0] + c0[3]*w1[2]
                      + c1[0]*w2[0] + c1[1]*w2[2] + c1[2]*w3[0] + c1[3]*w3[2];
            float s2y = c0[0]*w0[1] + c0[1]*w0[3] + c0[2]*w1[1] + c0[3]*w1[3]
                      + c1[0]*w2[1] + c1[1]*w2[3] + c1[2]*w3[1] + c1[3]*w3[3];
            float s3x = d0[0]*w0[0] + d0[1]*w0[2] + d0[2]*w1[0] + d0[3]*w1[2]
                      + d1[0]*w2[0] + d1[1]*w2[2] + d1[2]*w3[0] + d1[3]*w3[2];
            float s3y = d0[0]*w0[1] + d0[1]*w0[3] + d0[2]*w1[1] + d0[3]*w1[3]
                      + d1[0]*w2[1] + d1[1]*w2[3] + d1[2]*w3[1] + d1[3]*w3[3];
#pragma unroll
            for (int off = 32; off; off >>= 1) {        // 8 chains interleaved
                s0x += __shfl_xor(s0x, off); s0y += __shfl_xor(s0y, off);
                s1x += __shfl_xor(s1x, off); s1y += __shfl_xor(s1y, off);
                s2x += __shfl_xor(s2x, off); s2y += __shfl_xor(s2y, off);
                s3x += __shfl_xor(s3x, off); s3y += __shfl_xor(s3y, off);
            }
            if (node + lane < N_NODES) {                // static accumulator select
                if      (lane == 0) t2[node]     = make_float2(s0x, s0y);
                else if (lane == 1) t2[node + 1] = make_float2(s1x, s1y);
                else if (lane == 2) t2[node + 2] = make_float2(s2x, s2y);
                else if (lane == 3) t2[node + 3] = make_float2(s3x, s3y);
            }
        }
    }
    grid.sync();

    // ---------------- P4: degree -> dinv, scale t2 ----------------
    for (int b = blockIdx.x; b < NBUCK; b += G) {
        int* cnt = smem;
        if (tid < 256) cnt[tid] = 0;
        __syncthreads();
        int s = bbase[b], e = bbase[b + 1];
        for (int i = s + tid; i < e; i += 1024)
            atomicAdd(&cnt[binned[i] >> 20], 1);
        __syncthreads();
        if (tid < 256) {
            int node = (b << 8) + tid;
            if (node < N_NODES) {
                float di = rsqrtf((float)(cnt[tid] + 1));  // +1 self loop
                dinv[node] = di;
                float2 t = t2[node];
                t2[node] = make_float2(t.x * di, t.y * di);
            }
        }
        __syncthreads();
    }
    grid.sync();

    // ---------------- P5: accumulate + fused epilogue ----------------
    for (int b = blockIdx.x; b < NBUCK; b += G) {
        float* a0 = reinterpret_cast<float*>(smem);
        float* a1 = a0 + 256;
        if (tid < 256) { a0[tid] = 0.f; a1[tid] = 0.f; }
        __syncthreads();
        int s = bbase[b], e = bbase[b + 1];
        for (int i = s + tid; i < e; i += 1024) {
            int vv = binned[i];
            float2 ts = t2[vv & 0xFFFFF];   // L2-resident 800 KB table
            atomicAdd(&a0[vv >> 20], ts.x);
            atomicAdd(&a1[vv >> 20], ts.y);
        }
        __syncthreads();
        if (tid < 256) {
            int node = (b << 8) + tid;
            if (node < N_NODES) {
                float2 self = t2[node];     // already dinv-scaled
                float di = dinv[node];
                out[node] = make_float2(di * (a0[tid] + self.x) + bconst[0],
                                        di * (a1[tid] + self.y) + bconst[1]);
            }
        }
        __syncthreads();
    }
}

extern "C" void kernel_launch(void* const* d_in, const int* in_sizes, int n_in,
                              void* d_out, int out_size, void* d_ws, size_t ws_size,
                              hipStream_t stream) {
    const int*   ei = (const int*)d_in[1];
    const float* x  = (const float*)d_in[0];
    const float* W1 = (const float*)d_in[2];
    const float* b1 = (const float*)d_in[3];
    const float* W2 = (const float*)d_in[4];
    const float* b2 = (const float*)d_in[5];

    char* ws = (char*)d_ws;
    int*    hist   = (int*)   (ws + 0);
    int*    coltot = (int*)   (ws + 800768);
    int*    bbase  = (int*)   (ws + 802336);
    float*  Wc     = (float*) (ws + 803904);
    float*  bconst = (float*) (ws + 808000);
    float*  dinv   = (float*) (ws + 808016);
    float2* t2     = (float2*)(ws + 1208016);
    int*    binned = (int*)   (ws + 2008016);
    float2* outp   = (float2*)d_out;

    static int occ = -1;                      // co-residency (cached)
    if (occ < 0) {
        if (hipOccupancyMaxActiveBlocksPerMultiprocessor(&occ, k_mega, 1024, 0)
                != hipSuccess || occ < 1)
            occ = 1;
    }
    int G = occ * 256;                        // 256 CUs on MI355X
    if (G > 512) G = 512;

    void* args[] = {(void*)&ei, (void*)&x, (void*)&W1, (void*)&b1,
                    (void*)&W2, (void*)&b2, (void*)&hist, (void*)&coltot,
                    (void*)&bbase, (void*)&Wc, (void*)&bconst, (void*)&dinv,
                    (void*)&t2, (void*)&binned, (void*)&outp};
    hipLaunchCooperativeKernel((void*)k_mega, dim3(G), dim3(1024), args, 0,
                               stream);
}